// Round 11
// baseline (126.665 us; speedup 1.0000x reference)
//
#include <hip/hip_runtime.h>
#include <math.h>

#define BB 64
#define SS 2048
#define DD 512
#define NU 512
#define WIN 128

__device__ __forceinline__ float wave_reduce_sum(float v) {
    #pragma unroll
    for (int off = 32; off > 0; off >>= 1)
        v += __shfl_down(v, off, 64);
    return v;
}

__device__ __forceinline__ float wave_reduce_max(float v) {
    #pragma unroll
    for (int off = 32; off > 0; off >>= 1)
        v = fmaxf(v, __shfl_down(v, off, 64));
    return v;
}

// Fused kernel 1.
// Blocks [0, 512): score, thread-per-row GEMV. block -> batch b = bid>>3,
//   row = (bid&7)*256 + tid. No cross-lane ops in the hot loop: each thread
//   streams its own 2 KiB key row (128 float4 loads, 8 per 128B line) against
//   q broadcast from LDS. Row loads are independent -> deep MLP, latency hidden.
// Blocks [512, 576): predictive-alignment params {g, start, end} per batch.
__global__ __launch_bounds__(256) void score_p_kernel(const float* __restrict__ query,
                                                      const float* __restrict__ keys,
                                                      const int* __restrict__ key_lengths,
                                                      const float* __restrict__ Wq,
                                                      const float* __restrict__ wp,
                                                      float* __restrict__ score,
                                                      float* __restrict__ ws) {
    __shared__ float qs[DD];
    __shared__ float act[NU];
    __shared__ float wsum[4];

    const int t = threadIdx.x;

    if (blockIdx.x < BB * 8) {
        // ---- score path ----
        const int b = blockIdx.x >> 3;
        const int r = ((blockIdx.x & 7) << 8) + t;

        if (t < DD / 4)
            ((float4*)qs)[t] = ((const float4*)(query + b * DD))[t];
        __syncthreads();

        const float4* rowv = (const float4*)(keys + ((size_t)b * SS + r) * DD);
        const float4* qv4  = (const float4*)qs;

        float acc = 0.f;
        #pragma unroll 8
        for (int j = 0; j < DD / 4; ++j) {
            const float4 k = rowv[j];
            const float4 q = qv4[j];
            acc += k.x * q.x + k.y * q.y + k.z * q.z + k.w * q.w;
        }
        score[b * SS + r] = acc;
    } else {
        // ---- p path: one block per batch ----
        const int b = blockIdx.x - BB * 8;
        const int wave = t >> 6;
        const int lane = t & 63;

        const float4* qv = (const float4*)(query + b * DD);
        const float4 q0 = qv[lane], q1 = qv[lane + 64];

        for (int u = wave; u < NU; u += 4) {
            const float4* wv = (const float4*)(Wq + (size_t)u * DD);
            const float4 w0 = wv[lane], w1 = wv[lane + 64];
            float p = q0.x*w0.x + q0.y*w0.y + q0.z*w0.z + q0.w*w0.w
                    + q1.x*w1.x + q1.y*w1.y + q1.z*w1.z + q1.w*w1.w;
            p = wave_reduce_sum(p);
            if (lane == 0) act[u] = tanhf(p);
        }
        __syncthreads();

        float sv = act[t] * wp[t] + act[t + 256] * wp[t + 256];
        sv = wave_reduce_sum(sv);
        if (lane == 0) wsum[wave] = sv;
        __syncthreads();

        if (t == 0) {
            const float s = wsum[0] + wsum[1] + wsum[2] + wsum[3];
            const float sig = 1.0f / (1.0f + expf(-s));
            const float L = (float)key_lengths[b];
            const float p = L * sig;
            const int start = (int)(p - (float)WIN);   // trunc toward zero
            const int end   = (int)(p + (float)WIN);
            const float diff = L - p;
            const float g = expf(-(diff * diff) / (float)WIN);
            ws[b] = g;
            ((int*)ws)[BB + b]     = start;
            ((int*)ws)[2 * BB + b] = end;
        }
    }
}

// Kernel 2: softmax stats + windowed weighted key sum.
// grid (B, 8) x 256 threads: block owns 64 d-columns; 4 waves split window rows.
__global__ __launch_bounds__(256) void ctx_kernel(const float* __restrict__ keys,
                                                  const float* __restrict__ score,
                                                  const float* __restrict__ ws,
                                                  float* __restrict__ ctx) {
    const int b      = blockIdx.x;
    const int dchunk = blockIdx.y;
    const int t      = threadIdx.x;
    const int wave   = t >> 6;
    const int lane   = t & 63;

    __shared__ float w_lds[2 * WIN + 4];
    __shared__ float redm[4], reds[4];
    __shared__ float part[4][64];

    const float* srow = score + b * SS;

    // softmax stats over S=2048: each thread loads 8 scores (2 x float4)
    const float4 v0 = ((const float4*)srow)[t];
    const float4 v1 = ((const float4*)srow)[t + 256];
    float m = fmaxf(fmaxf(fmaxf(v0.x, v0.y), fmaxf(v0.z, v0.w)),
                    fmaxf(fmaxf(v1.x, v1.y), fmaxf(v1.z, v1.w)));
    m = wave_reduce_max(m);
    if (lane == 0) redm[wave] = m;
    __syncthreads();
    const float mx = fmaxf(fmaxf(redm[0], redm[1]), fmaxf(redm[2], redm[3]));

    float sum = expf(v0.x - mx) + expf(v0.y - mx) + expf(v0.z - mx) + expf(v0.w - mx)
              + expf(v1.x - mx) + expf(v1.y - mx) + expf(v1.z - mx) + expf(v1.w - mx);
    sum = wave_reduce_sum(sum);
    if (lane == 0) reds[wave] = sum;
    __syncthreads();
    const float inv = 1.0f / (reds[0] + reds[1] + reds[2] + reds[3]);

    const float g = ws[b];
    const int start = ((const int*)ws)[BB + b];
    const int end   = ((const int*)ws)[2 * BB + b];
    const int s_lo = max(start, 0);
    const int s_hi = min(end, SS);
    const int width = s_hi - s_lo;   // <= 257

    for (int i = t; i < width; i += 256)
        w_lds[i] = expf(srow[s_lo + i] - mx) * inv * g;
    __syncthreads();

    // accumulate: lane owns column d; waves stride the window rows
    const int d = dchunk * 64 + lane;
    const float* kb = keys + (size_t)b * SS * DD + (size_t)s_lo * DD + d;
    float acc = 0.f;
    for (int i = wave; i < width; i += 4)
        acc += w_lds[i] * kb[(size_t)i * DD];

    if (wave != 0) part[wave][lane] = acc;
    __syncthreads();
    if (wave == 0)
        ctx[b * DD + d] = acc + part[1][lane] + part[2][lane] + part[3][lane];
}

extern "C" void kernel_launch(void* const* d_in, const int* in_sizes, int n_in,
                              void* d_out, int out_size, void* d_ws, size_t ws_size,
                              hipStream_t stream) {
    const float* query       = (const float*)d_in[0];
    const float* keys        = (const float*)d_in[1];
    const int*   key_lengths = (const int*)d_in[2];
    const float* Wq          = (const float*)d_in[3];
    const float* wp          = (const float*)d_in[4];

    float* ctx   = (float*)d_out;             // [64, 512]
    float* score = (float*)d_out + BB * DD;   // [64, 2048]
    float* ws    = (float*)d_ws;              // {g[64], start[64], end[64]}

    hipLaunchKernelGGL(score_p_kernel, dim3(BB * 8 + BB), dim3(256), 0, stream,
                       query, keys, key_lengths, Wq, wp, score, ws);
    hipLaunchKernelGGL(ctx_kernel, dim3(BB, 8), dim3(256), 0, stream,
                       keys, score, ws, ctx);
}

// Round 12
// 125.762 us; speedup vs baseline: 1.0072x; 1.0072x over previous
//
#include <hip/hip_runtime.h>
#include <math.h>

#define BB 64
#define SS 2048
#define DD 512
#define NU 512
#define WIN 128

__device__ __forceinline__ float wave_reduce_sum(float v) {
    #pragma unroll
    for (int off = 32; off > 0; off >>= 1)
        v += __shfl_down(v, off, 64);
    return v;
}

__device__ __forceinline__ float wave_reduce_max(float v) {
    #pragma unroll
    for (int off = 32; off > 0; off >>= 1)
        v = fmaxf(v, __shfl_down(v, off, 64));
    return v;
}

__device__ __forceinline__ float dot4(const float4 a, const float4 b) {
    return a.x * b.x + a.y * b.y + a.z * b.z + a.w * b.w;
}

// Fused kernel 1.
// Blocks [0, 2048): score. 16-lanes-per-row GEMV: wave covers 4 rows/pass
//   (group g = lane>>4 -> row, w = lane&15 -> 256B segment), 4 passes = 16
//   rows/wave, 64 rows/block. q held in 8 float4 regs (loop-invariant).
//   Reduce = 4 shfl_xor levels, one instruction reduces all 4 rows at once.
//   2048 blocks = 8/CU -> 32 waves/CU of latency-hiding.
// Blocks [2048, 2112): predictive-alignment params {g, start, end} per batch.
__global__ __launch_bounds__(256) void score_p_kernel(const float* __restrict__ query,
                                                      const float* __restrict__ keys,
                                                      const int* __restrict__ key_lengths,
                                                      const float* __restrict__ Wq,
                                                      const float* __restrict__ wp,
                                                      float* __restrict__ score,
                                                      float* __restrict__ ws) {
    const int t = threadIdx.x;

    if (blockIdx.x < BB * 32) {
        // ---- score path ----
        const int b     = blockIdx.x >> 5;   // 32 blocks per batch
        const int chunk = blockIdx.x & 31;   // 64 rows per block
        const int wave  = t >> 6;
        const int lane  = t & 63;
        const int g     = lane >> 4;         // group -> row within pass
        const int w     = lane & 15;         // 16 lanes span one row
        const int r0    = chunk * 64 + wave * 16;

        const float4* qv = (const float4*)(query + b * DD);
        const float4 q0 = qv[w],       q1 = qv[16 + w],  q2 = qv[32 + w],  q3 = qv[48 + w];
        const float4 q4 = qv[64 + w],  q5 = qv[80 + w],  q6 = qv[96 + w],  q7 = qv[112 + w];

        const float4* kb = (const float4*)(keys + (size_t)b * SS * DD);

        #pragma unroll
        for (int p = 0; p < 4; ++p) {
            const int r = r0 + p * 4 + g;
            const float4* rv = kb + (size_t)r * (DD / 4);
            const float4 k0 = rv[w],       k1 = rv[16 + w],  k2 = rv[32 + w],  k3 = rv[48 + w];
            const float4 k4 = rv[64 + w],  k5 = rv[80 + w],  k6 = rv[96 + w],  k7 = rv[112 + w];

            const float s0 = dot4(k0, q0), s1 = dot4(k1, q1), s2 = dot4(k2, q2), s3 = dot4(k3, q3);
            const float s4 = dot4(k4, q4), s5 = dot4(k5, q5), s6 = dot4(k6, q6), s7 = dot4(k7, q7);
            float acc = ((s0 + s1) + (s2 + s3)) + ((s4 + s5) + (s6 + s7));

            // reduce within each 16-lane group (all 4 rows in parallel)
            #pragma unroll
            for (int m = 1; m < 16; m <<= 1)
                acc += __shfl_xor(acc, m, 64);

            if (w == 0) score[b * SS + r] = acc;
        }
    } else {
        // ---- p path: one block per batch ----
        const int b = blockIdx.x - BB * 32;
        const int wave = t >> 6;
        const int lane = t & 63;
        __shared__ float act[NU];
        __shared__ float wsum[4];

        const float4* qv = (const float4*)(query + b * DD);
        const float4 q0 = qv[lane], q1 = qv[lane + 64];

        for (int u = wave; u < NU; u += 4) {
            const float4* wv = (const float4*)(Wq + (size_t)u * DD);
            const float4 w0 = wv[lane], w1 = wv[lane + 64];
            float p = dot4(q0, w0) + dot4(q1, w1);
            p = wave_reduce_sum(p);
            if (lane == 0) act[u] = tanhf(p);
        }
        __syncthreads();

        float sv = act[t] * wp[t] + act[t + 256] * wp[t + 256];
        sv = wave_reduce_sum(sv);
        if (lane == 0) wsum[wave] = sv;
        __syncthreads();

        if (t == 0) {
            const float s = wsum[0] + wsum[1] + wsum[2] + wsum[3];
            const float sig = 1.0f / (1.0f + expf(-s));
            const float L = (float)key_lengths[b];
            const float p = L * sig;
            const int start = (int)(p - (float)WIN);   // trunc toward zero
            const int end   = (int)(p + (float)WIN);
            const float diff = L - p;
            const float g = expf(-(diff * diff) / (float)WIN);
            ws[b] = g;
            ((int*)ws)[BB + b]     = start;
            ((int*)ws)[2 * BB + b] = end;
        }
    }
}

// Kernel 2: softmax stats + windowed weighted key sum.
// grid (B, 8) x 256 threads: block owns 64 d-columns; 4 waves split window rows.
__global__ __launch_bounds__(256) void ctx_kernel(const float* __restrict__ keys,
                                                  const float* __restrict__ score,
                                                  const float* __restrict__ ws,
                                                  float* __restrict__ ctx) {
    const int b      = blockIdx.x;
    const int dchunk = blockIdx.y;
    const int t      = threadIdx.x;
    const int wave   = t >> 6;
    const int lane   = t & 63;

    __shared__ float w_lds[2 * WIN + 4];
    __shared__ float redm[4], reds[4];
    __shared__ float part[4][64];

    const float* srow = score + b * SS;

    // softmax stats over S=2048: each thread loads 8 scores (2 x float4)
    const float4 v0 = ((const float4*)srow)[t];
    const float4 v1 = ((const float4*)srow)[t + 256];
    float m = fmaxf(fmaxf(fmaxf(v0.x, v0.y), fmaxf(v0.z, v0.w)),
                    fmaxf(fmaxf(v1.x, v1.y), fmaxf(v1.z, v1.w)));
    m = wave_reduce_max(m);
    if (lane == 0) redm[wave] = m;
    __syncthreads();
    const float mx = fmaxf(fmaxf(redm[0], redm[1]), fmaxf(redm[2], redm[3]));

    float sum = expf(v0.x - mx) + expf(v0.y - mx) + expf(v0.z - mx) + expf(v0.w - mx)
              + expf(v1.x - mx) + expf(v1.y - mx) + expf(v1.z - mx) + expf(v1.w - mx);
    sum = wave_reduce_sum(sum);
    if (lane == 0) reds[wave] = sum;
    __syncthreads();
    const float inv = 1.0f / (reds[0] + reds[1] + reds[2] + reds[3]);

    const float g = ws[b];
    const int start = ((const int*)ws)[BB + b];
    const int end   = ((const int*)ws)[2 * BB + b];
    const int s_lo = max(start, 0);
    const int s_hi = min(end, SS);
    const int width = s_hi - s_lo;   // <= 257

    for (int i = t; i < width; i += 256)
        w_lds[i] = expf(srow[s_lo + i] - mx) * inv * g;
    __syncthreads();

    // accumulate: lane owns column d; waves stride the window rows
    const int d = dchunk * 64 + lane;
    const float* kb = keys + (size_t)b * SS * DD + (size_t)s_lo * DD + d;
    float acc = 0.f;
    for (int i = wave; i < width; i += 4)
        acc += w_lds[i] * kb[(size_t)i * DD];

    if (wave != 0) part[wave][lane] = acc;
    __syncthreads();
    if (wave == 0)
        ctx[b * DD + d] = acc + part[1][lane] + part[2][lane] + part[3][lane];
}

extern "C" void kernel_launch(void* const* d_in, const int* in_sizes, int n_in,
                              void* d_out, int out_size, void* d_ws, size_t ws_size,
                              hipStream_t stream) {
    const float* query       = (const float*)d_in[0];
    const float* keys        = (const float*)d_in[1];
    const int*   key_lengths = (const int*)d_in[2];
    const float* Wq          = (const float*)d_in[3];
    const float* wp          = (const float*)d_in[4];

    float* ctx   = (float*)d_out;             // [64, 512]
    float* score = (float*)d_out + BB * DD;   // [64, 2048]
    float* ws    = (float*)d_ws;              // {g[64], start[64], end[64]}

    hipLaunchKernelGGL(score_p_kernel, dim3(BB * 32 + BB), dim3(256), 0, stream,
                       query, keys, key_lengths, Wq, wp, score, ws);
    hipLaunchKernelGGL(ctx_kernel, dim3(BB, 8), dim3(256), 0, stream,
                       keys, score, ws, ctx);
}

// Round 13
// 75.330 us; speedup vs baseline: 1.6815x; 1.6695x over previous
//
#include <hip/hip_runtime.h>
#include <math.h>

#define BB 64
#define SS 2048
#define DD 512
#define NU 512
#define WIN 128
#define NSLICE 4
#define PART_OFF 1024   // float offset of partials inside d_ws

__device__ __forceinline__ float wave_reduce_sum(float v) {
    #pragma unroll
    for (int off = 32; off > 0; off >>= 1)
        v += __shfl_down(v, off, 64);
    return v;
}

__device__ __forceinline__ float wave_reduce_max(float v) {
    #pragma unroll
    for (int off = 32; off > 0; off >>= 1)
        v = fmaxf(v, __shfl_down(v, off, 64));
    return v;
}

__device__ __forceinline__ float dot4(const float4 a, const float4 b) {
    return a.x * b.x + a.y * b.y + a.z * b.z + a.w * b.w;
}

// Kernel 1.
// Blocks [0, 64): p-path, SAME 16-lane-group GEMV structure as score
//   (4-level shfl, 8 independent loads/pass, 32 static passes) -> no serial
//   tail. Launched FIRST so it overlaps the score blocks.
// Blocks [64, 64+2048): score, 16-lanes-per-row GEMV (unchanged from R12).
__global__ __launch_bounds__(256) void score_p_kernel(const float* __restrict__ query,
                                                      const float* __restrict__ keys,
                                                      const int* __restrict__ key_lengths,
                                                      const float* __restrict__ Wq,
                                                      const float* __restrict__ wp,
                                                      float* __restrict__ score,
                                                      float* __restrict__ ws) {
    const int t    = threadIdx.x;
    const int wave = t >> 6;
    const int lane = t & 63;
    const int g    = lane >> 4;   // 4 rows (or units) per wave pass
    const int w    = lane & 15;   // 16 lanes span one 512-float row

    if (blockIdx.x < BB) {
        // ---- p path: one block per batch, GEMV over Wq then wp-reduce ----
        const int b = blockIdx.x;
        __shared__ float act[NU];
        __shared__ float wsum[4];

        const float4* qv = (const float4*)(query + b * DD);
        const float4 q0 = qv[w],       q1 = qv[16 + w],  q2 = qv[32 + w],  q3 = qv[48 + w];
        const float4 q4 = qv[64 + w],  q5 = qv[80 + w],  q6 = qv[96 + w],  q7 = qv[112 + w];

        #pragma unroll 2
        for (int pass = 0; pass < 32; ++pass) {
            const int u = pass * 16 + wave * 4 + g;
            const float4* rv = (const float4*)(Wq + (size_t)u * DD);
            const float4 k0 = rv[w],       k1 = rv[16 + w],  k2 = rv[32 + w],  k3 = rv[48 + w];
            const float4 k4 = rv[64 + w],  k5 = rv[80 + w],  k6 = rv[96 + w],  k7 = rv[112 + w];
            const float s0 = dot4(k0, q0), s1 = dot4(k1, q1), s2 = dot4(k2, q2), s3 = dot4(k3, q3);
            const float s4 = dot4(k4, q4), s5 = dot4(k5, q5), s6 = dot4(k6, q6), s7 = dot4(k7, q7);
            float acc = ((s0 + s1) + (s2 + s3)) + ((s4 + s5) + (s6 + s7));
            #pragma unroll
            for (int m = 1; m < 16; m <<= 1)
                acc += __shfl_xor(acc, m, 64);
            if (w == 0) act[u] = tanhf(acc);
        }
        __syncthreads();

        float sv = act[t] * wp[t] + act[t + 256] * wp[t + 256];
        sv = wave_reduce_sum(sv);
        if (lane == 0) wsum[wave] = sv;
        __syncthreads();

        if (t == 0) {
            const float s = wsum[0] + wsum[1] + wsum[2] + wsum[3];
            const float sig = 1.0f / (1.0f + expf(-s));
            const float L = (float)key_lengths[b];
            const float p = L * sig;
            const int start = (int)(p - (float)WIN);   // trunc toward zero
            const int end   = (int)(p + (float)WIN);
            const float diff = L - p;
            const float gg = expf(-(diff * diff) / (float)WIN);
            ws[b] = gg;
            ((int*)ws)[BB + b]     = start;
            ((int*)ws)[2 * BB + b] = end;
        }
    } else {
        // ---- score path ----
        const int bid   = blockIdx.x - BB;
        const int b     = bid >> 5;   // 32 blocks per batch
        const int chunk = bid & 31;   // 64 rows per block
        const int r0    = chunk * 64 + wave * 16;

        const float4* qv = (const float4*)(query + b * DD);
        const float4 q0 = qv[w],       q1 = qv[16 + w],  q2 = qv[32 + w],  q3 = qv[48 + w];
        const float4 q4 = qv[64 + w],  q5 = qv[80 + w],  q6 = qv[96 + w],  q7 = qv[112 + w];

        const float4* kb = (const float4*)(keys + (size_t)b * SS * DD);

        #pragma unroll
        for (int p = 0; p < 4; ++p) {
            const int r = r0 + p * 4 + g;
            const float4* rv = kb + (size_t)r * (DD / 4);
            const float4 k0 = rv[w],       k1 = rv[16 + w],  k2 = rv[32 + w],  k3 = rv[48 + w];
            const float4 k4 = rv[64 + w],  k5 = rv[80 + w],  k6 = rv[96 + w],  k7 = rv[112 + w];
            const float s0 = dot4(k0, q0), s1 = dot4(k1, q1), s2 = dot4(k2, q2), s3 = dot4(k3, q3);
            const float s4 = dot4(k4, q4), s5 = dot4(k5, q5), s6 = dot4(k6, q6), s7 = dot4(k7, q7);
            float acc = ((s0 + s1) + (s2 + s3)) + ((s4 + s5) + (s6 + s7));
            #pragma unroll
            for (int m = 1; m < 16; m <<= 1)
                acc += __shfl_xor(acc, m, 64);
            if (w == 0) score[b * SS + r] = acc;
        }
    }
}

// Kernel 2 (stage A): softmax stats + windowed weighted sum over a contiguous
// window SLICE, streamed linearly. grid (B, NSLICE) x 256: 256 threads cover
// 2 full rows per step (4 KB contiguous); thread owns 4 fixed columns.
__global__ __launch_bounds__(256) void ctxA_kernel(const float* __restrict__ keys,
                                                   const float* __restrict__ score,
                                                   const float* __restrict__ ws,
                                                   float* __restrict__ part) {
    const int b     = blockIdx.x;
    const int slice = blockIdx.y;
    const int t     = threadIdx.x;
    const int wave  = t >> 6;
    const int lane  = t & 63;

    __shared__ float w_lds[80];          // <= ceil(257/4)+pad slice rows
    __shared__ float redm[4], reds[4];
    __shared__ float4 part_l[128];

    const float* srow = score + b * SS;

    // softmax stats over S=2048
    const float4 v0 = ((const float4*)srow)[t];
    const float4 v1 = ((const float4*)srow)[t + 256];
    float m = fmaxf(fmaxf(fmaxf(v0.x, v0.y), fmaxf(v0.z, v0.w)),
                    fmaxf(fmaxf(v1.x, v1.y), fmaxf(v1.z, v1.w)));
    m = wave_reduce_max(m);
    if (lane == 0) redm[wave] = m;
    __syncthreads();
    const float mx = fmaxf(fmaxf(redm[0], redm[1]), fmaxf(redm[2], redm[3]));

    float sum = expf(v0.x - mx) + expf(v0.y - mx) + expf(v0.z - mx) + expf(v0.w - mx)
              + expf(v1.x - mx) + expf(v1.y - mx) + expf(v1.z - mx) + expf(v1.w - mx);
    sum = wave_reduce_sum(sum);
    if (lane == 0) reds[wave] = sum;
    __syncthreads();
    const float inv = 1.0f / (reds[0] + reds[1] + reds[2] + reds[3]);

    const float gg   = ws[b];
    const int start  = ((const int*)ws)[BB + b];
    const int end    = ((const int*)ws)[2 * BB + b];
    const int s_lo   = max(start, 0);
    const int s_hi   = min(end, SS);
    const int width  = s_hi - s_lo;              // in [128, 257]
    const int sliceN = (width + NSLICE - 1) / NSLICE;
    const int i_lo   = slice * sliceN;
    const int i_hi   = min(i_lo + sliceN, width);
    const int n      = i_hi - i_lo;              // may be <= 0

    for (int i = t; i < n; i += 256)
        w_lds[i] = expf(srow[s_lo + i_lo + i] - mx) * inv * gg;
    __syncthreads();

    // linear stream: 2 rows x 128 float4-cols per step, thread owns col group c4
    const int myrow = t >> 7;        // 0 or 1
    const int c4    = t & 127;
    const float4* kb = (const float4*)(keys + ((size_t)b * SS + s_lo + i_lo) * DD);

    float4 acc = make_float4(0.f, 0.f, 0.f, 0.f);
    for (int i = myrow; i < n; i += 2) {
        const float4 k = kb[(size_t)i * (DD / 4) + c4];
        const float wg = w_lds[i];
        acc.x += wg * k.x; acc.y += wg * k.y; acc.z += wg * k.z; acc.w += wg * k.w;
    }

    if (myrow) part_l[c4] = acc;
    __syncthreads();
    if (!myrow) {
        const float4 o = part_l[c4];
        acc.x += o.x; acc.y += o.y; acc.z += o.z; acc.w += o.w;
        ((float4*)part)[((size_t)b * NSLICE + slice) * 128 + c4] = acc;
    }
}

// Kernel 2 (stage B): ctx[b][d] = sum over slices of partials
__global__ __launch_bounds__(512) void ctxB_kernel(const float* __restrict__ part,
                                                   float* __restrict__ ctx) {
    const int b = blockIdx.x;
    const int d = threadIdx.x;
    float s = 0.f;
    #pragma unroll
    for (int sl = 0; sl < NSLICE; ++sl)
        s += part[((size_t)b * NSLICE + sl) * DD + d];
    ctx[b * DD + d] = s;
}

extern "C" void kernel_launch(void* const* d_in, const int* in_sizes, int n_in,
                              void* d_out, int out_size, void* d_ws, size_t ws_size,
                              hipStream_t stream) {
    const float* query       = (const float*)d_in[0];
    const float* keys        = (const float*)d_in[1];
    const int*   key_lengths = (const int*)d_in[2];
    const float* Wq          = (const float*)d_in[3];
    const float* wp          = (const float*)d_in[4];

    float* ctx   = (float*)d_out;             // [64, 512]
    float* score = (float*)d_out + BB * DD;   // [64, 2048]
    float* ws    = (float*)d_ws;              // {g[64], start[64], end[64]}
    float* part  = (float*)d_ws + PART_OFF;   // [64, NSLICE, 512]

    hipLaunchKernelGGL(score_p_kernel, dim3(BB + BB * 32), dim3(256), 0, stream,
                       query, keys, key_lengths, Wq, wp, score, ws);
    hipLaunchKernelGGL(ctxA_kernel, dim3(BB, NSLICE), dim3(256), 0, stream,
                       keys, score, ws, part);
    hipLaunchKernelGGL(ctxB_kernel, dim3(BB), dim3(512), 0, stream,
                       part, ctx);
}

// Round 14
// 67.392 us; speedup vs baseline: 1.8795x; 1.1178x over previous
//
#include <hip/hip_runtime.h>
#include <math.h>

#define BB 64
#define SS 2048
#define DD 512
#define NU 512
#define WIN 128
#define NSLICE 4
#define PART_OFF 1024   // float offset of partials inside d_ws

__device__ __forceinline__ float wave_reduce_sum(float v) {
    #pragma unroll
    for (int off = 32; off > 0; off >>= 1)
        v += __shfl_down(v, off, 64);
    return v;
}

__device__ __forceinline__ float wave_reduce_max(float v) {
    #pragma unroll
    for (int off = 32; off > 0; off >>= 1)
        v = fmaxf(v, __shfl_down(v, off, 64));
    return v;
}

__device__ __forceinline__ float dot4(const float4 a, const float4 b) {
    return a.x * b.x + a.y * b.y + a.z * b.z + a.w * b.w;
}

// Kernel 1.
// Blocks [0, 64): p-path (16-lane-group GEMV over Wq, launched first).
// Blocks [64, 64+2048): score, 16-lanes-per-row GEMV with a 2-deep software
//   pipeline: pass p+1's 8 row-loads are issued before pass p's reduction.
//   __launch_bounds__(256, 4) raises the VGPR cap to ~128 so ~16 float4
//   loads stay in flight per lane (R12's VGPR=32 allowed only ~4).
__global__ __launch_bounds__(256, 4) void score_p_kernel(const float* __restrict__ query,
                                                         const float* __restrict__ keys,
                                                         const int* __restrict__ key_lengths,
                                                         const float* __restrict__ Wq,
                                                         const float* __restrict__ wp,
                                                         float* __restrict__ score,
                                                         float* __restrict__ ws) {
    const int t    = threadIdx.x;
    const int wave = t >> 6;
    const int lane = t & 63;
    const int g    = lane >> 4;   // 4 rows per wave pass
    const int w    = lane & 15;   // 16 lanes span one 512-float row

    if (blockIdx.x < BB) {
        // ---- p path: one block per batch ----
        const int b = blockIdx.x;
        __shared__ float act[NU];
        __shared__ float wsum[4];

        const float4* qv = (const float4*)(query + b * DD);
        const float4 q0 = qv[w],       q1 = qv[16 + w],  q2 = qv[32 + w],  q3 = qv[48 + w];
        const float4 q4 = qv[64 + w],  q5 = qv[80 + w],  q6 = qv[96 + w],  q7 = qv[112 + w];

        #pragma unroll 2
        for (int pass = 0; pass < 32; ++pass) {
            const int u = pass * 16 + wave * 4 + g;
            const float4* rv = (const float4*)(Wq + (size_t)u * DD);
            const float4 k0 = rv[w],       k1 = rv[16 + w],  k2 = rv[32 + w],  k3 = rv[48 + w];
            const float4 k4 = rv[64 + w],  k5 = rv[80 + w],  k6 = rv[96 + w],  k7 = rv[112 + w];
            const float s0 = dot4(k0, q0), s1 = dot4(k1, q1), s2 = dot4(k2, q2), s3 = dot4(k3, q3);
            const float s4 = dot4(k4, q4), s5 = dot4(k5, q5), s6 = dot4(k6, q6), s7 = dot4(k7, q7);
            float acc = ((s0 + s1) + (s2 + s3)) + ((s4 + s5) + (s6 + s7));
            #pragma unroll
            for (int m = 1; m < 16; m <<= 1)
                acc += __shfl_xor(acc, m, 64);
            if (w == 0) act[u] = tanhf(acc);
        }
        __syncthreads();

        float sv = act[t] * wp[t] + act[t + 256] * wp[t + 256];
        sv = wave_reduce_sum(sv);
        if (lane == 0) wsum[wave] = sv;
        __syncthreads();

        if (t == 0) {
            const float s = wsum[0] + wsum[1] + wsum[2] + wsum[3];
            const float sig = 1.0f / (1.0f + expf(-s));
            const float L = (float)key_lengths[b];
            const float p = L * sig;
            const int start = (int)(p - (float)WIN);   // trunc toward zero
            const int end   = (int)(p + (float)WIN);
            const float diff = L - p;
            const float gg = expf(-(diff * diff) / (float)WIN);
            ws[b] = gg;
            ((int*)ws)[BB + b]     = start;
            ((int*)ws)[2 * BB + b] = end;
        }
    } else {
        // ---- score path: software-pipelined 16-lane-group GEMV ----
        const int bid   = blockIdx.x - BB;
        const int b     = bid >> 5;   // 32 blocks per batch
        const int chunk = bid & 31;   // 64 rows per block
        const int r0    = chunk * 64 + wave * 16;

        const float4* qv = (const float4*)(query + b * DD);
        const float4 q0 = qv[w],       q1 = qv[16 + w],  q2 = qv[32 + w],  q3 = qv[48 + w];
        const float4 q4 = qv[64 + w],  q5 = qv[80 + w],  q6 = qv[96 + w],  q7 = qv[112 + w];

        const float4* kb = (const float4*)(keys + (size_t)b * SS * DD);

        // prologue: load pass 0
        const float4* rv = kb + (size_t)(r0 + g) * (DD / 4);
        float4 k0 = rv[w],       k1 = rv[16 + w],  k2 = rv[32 + w],  k3 = rv[48 + w];
        float4 k4 = rv[64 + w],  k5 = rv[80 + w],  k6 = rv[96 + w],  k7 = rv[112 + w];

        #pragma unroll
        for (int p = 0; p < 4; ++p) {
            float4 n0, n1, n2, n3, n4, n5, n6, n7;
            if (p < 3) {   // issue next pass's loads before this pass's reduce
                const float4* nv = kb + (size_t)(r0 + (p + 1) * 4 + g) * (DD / 4);
                n0 = nv[w];       n1 = nv[16 + w];  n2 = nv[32 + w];  n3 = nv[48 + w];
                n4 = nv[64 + w];  n5 = nv[80 + w];  n6 = nv[96 + w];  n7 = nv[112 + w];
            }
            const float s0 = dot4(k0, q0), s1 = dot4(k1, q1), s2 = dot4(k2, q2), s3 = dot4(k3, q3);
            const float s4 = dot4(k4, q4), s5 = dot4(k5, q5), s6 = dot4(k6, q6), s7 = dot4(k7, q7);
            float acc = ((s0 + s1) + (s2 + s3)) + ((s4 + s5) + (s6 + s7));
            #pragma unroll
            for (int m = 1; m < 16; m <<= 1)
                acc += __shfl_xor(acc, m, 64);
            if (w == 0) score[b * SS + r0 + p * 4 + g] = acc;
            if (p < 3) {
                k0 = n0; k1 = n1; k2 = n2; k3 = n3;
                k4 = n4; k5 = n5; k6 = n6; k7 = n7;
            }
        }
    }
}

// Kernel 2 (stage A): softmax stats + windowed weighted sum over a contiguous
// window SLICE, streamed linearly. grid (B, NSLICE) x 256.
__global__ __launch_bounds__(256) void ctxA_kernel(const float* __restrict__ keys,
                                                   const float* __restrict__ score,
                                                   const float* __restrict__ ws,
                                                   float* __restrict__ part) {
    const int b     = blockIdx.x;
    const int slice = blockIdx.y;
    const int t     = threadIdx.x;
    const int wave  = t >> 6;
    const int lane  = t & 63;

    __shared__ float w_lds[80];
    __shared__ float redm[4], reds[4];
    __shared__ float4 part_l[128];

    const float* srow = score + b * SS;

    const float4 v0 = ((const float4*)srow)[t];
    const float4 v1 = ((const float4*)srow)[t + 256];
    float m = fmaxf(fmaxf(fmaxf(v0.x, v0.y), fmaxf(v0.z, v0.w)),
                    fmaxf(fmaxf(v1.x, v1.y), fmaxf(v1.z, v1.w)));
    m = wave_reduce_max(m);
    if (lane == 0) redm[wave] = m;
    __syncthreads();
    const float mx = fmaxf(fmaxf(redm[0], redm[1]), fmaxf(redm[2], redm[3]));

    float sum = expf(v0.x - mx) + expf(v0.y - mx) + expf(v0.z - mx) + expf(v0.w - mx)
              + expf(v1.x - mx) + expf(v1.y - mx) + expf(v1.z - mx) + expf(v1.w - mx);
    sum = wave_reduce_sum(sum);
    if (lane == 0) reds[wave] = sum;
    __syncthreads();
    const float inv = 1.0f / (reds[0] + reds[1] + reds[2] + reds[3]);

    const float gg   = ws[b];
    const int start  = ((const int*)ws)[BB + b];
    const int end    = ((const int*)ws)[2 * BB + b];
    const int s_lo   = max(start, 0);
    const int s_hi   = min(end, SS);
    const int width  = s_hi - s_lo;              // in [0, 257]
    const int sliceN = (width + NSLICE - 1) / NSLICE;
    const int i_lo   = slice * sliceN;
    const int i_hi   = min(i_lo + sliceN, width);
    const int n      = i_hi - i_lo;              // may be <= 0

    for (int i = t; i < n; i += 256)
        w_lds[i] = expf(srow[s_lo + i_lo + i] - mx) * inv * gg;
    __syncthreads();

    const int myrow = t >> 7;        // 0 or 1
    const int c4    = t & 127;
    const float4* kb = (const float4*)(keys + ((size_t)b * SS + s_lo + i_lo) * DD);

    float4 acc = make_float4(0.f, 0.f, 0.f, 0.f);
    for (int i = myrow; i < n; i += 2) {
        const float4 k = kb[(size_t)i * (DD / 4) + c4];
        const float wg = w_lds[i];
        acc.x += wg * k.x; acc.y += wg * k.y; acc.z += wg * k.z; acc.w += wg * k.w;
    }

    if (myrow) part_l[c4] = acc;
    __syncthreads();
    if (!myrow) {
        const float4 o = part_l[c4];
        acc.x += o.x; acc.y += o.y; acc.z += o.z; acc.w += o.w;
        ((float4*)part)[((size_t)b * NSLICE + slice) * 128 + c4] = acc;
    }
}

// Kernel 2 (stage B): ctx[b][d] = sum over slices of partials
__global__ __launch_bounds__(512) void ctxB_kernel(const float* __restrict__ part,
                                                   float* __restrict__ ctx) {
    const int b = blockIdx.x;
    const int d = threadIdx.x;
    float s = 0.f;
    #pragma unroll
    for (int sl = 0; sl < NSLICE; ++sl)
        s += part[((size_t)b * NSLICE + sl) * DD + d];
    ctx[b * DD + d] = s;
}

extern "C" void kernel_launch(void* const* d_in, const int* in_sizes, int n_in,
                              void* d_out, int out_size, void* d_ws, size_t ws_size,
                              hipStream_t stream) {
    const float* query       = (const float*)d_in[0];
    const float* keys        = (const float*)d_in[1];
    const int*   key_lengths = (const int*)d_in[2];
    const float* Wq          = (const float*)d_in[3];
    const float* wp          = (const float*)d_in[4];

    float* ctx   = (float*)d_out;             // [64, 512]
    float* score = (float*)d_out + BB * DD;   // [64, 2048]
    float* ws    = (float*)d_ws;              // {g[64], start[64], end[64]}
    float* part  = (float*)d_ws + PART_OFF;   // [64, NSLICE, 512]

    hipLaunchKernelGGL(score_p_kernel, dim3(BB + BB * 32), dim3(256), 0, stream,
                       query, keys, key_lengths, Wq, wp, score, ws);
    hipLaunchKernelGGL(ctxA_kernel, dim3(BB, NSLICE), dim3(256), 0, stream,
                       keys, score, ws, part);
    hipLaunchKernelGGL(ctxB_kernel, dim3(BB), dim3(512), 0, stream,
                       part, ctx);
}